// Round 1
// baseline (309.052 us; speedup 1.0000x reference)
//
#include <hip/hip_runtime.h>
#include <hip/hip_bf16.h>

// Problem constants (match reference)
constexpr int cB  = 8;
constexpr int cS  = 4096;
constexpr int cH  = 768;
constexpr int cNH = 12;
constexpr int cL  = 2;
constexpr int cNS = 64;
constexpr int cDH = 64;
constexpr int cM  = cB * cNS;  // 512 rows of activations

typedef __attribute__((ext_vector_type(8))) short bf16x8;
typedef __attribute__((ext_vector_type(4))) float f32x4;

// ---------------------------------------------------------------------------
// 1) Segment-mean pooling: x_bf16[b*NS+n][H] = mean of start_layer rows whose
//    sent_ind == n (token 0 always excluded). One block per (b,n).
// ---------------------------------------------------------------------------
__global__ __launch_bounds__(256) void pool_kernel(
    const int* __restrict__ sent_ind, const float* __restrict__ sl,
    __hip_bfloat16* __restrict__ xb)
{
    int bn = blockIdx.x;
    int b = bn >> 6, n = bn & (cNS - 1);
    __shared__ int cnt;
    __shared__ int list[cS];
    if (threadIdx.x == 0) cnt = 0;
    __syncthreads();
    const int* si = sent_ind + (size_t)b * cS;
    for (int s = threadIdx.x; s < cS; s += 256)
        if (s != 0 && si[s] == n) { int p = atomicAdd(&cnt, 1); list[p] = s; }
    __syncthreads();
    int c = cnt;
    float a0 = 0.f, a1 = 0.f, a2 = 0.f;
    for (int i = 0; i < c; ++i) {
        const float* row = sl + ((size_t)b * cS + list[i]) * cH;
        a0 += row[threadIdx.x];
        a1 += row[threadIdx.x + 256];
        a2 += row[threadIdx.x + 512];
    }
    float inv = 1.0f / (float)c;
    __hip_bfloat16* xr = xb + (size_t)bn * cH;
    xr[threadIdx.x]       = __float2bfloat16(a0 * inv);
    xr[threadIdx.x + 256] = __float2bfloat16(a1 * inv);
    xr[threadIdx.x + 512] = __float2bfloat16(a2 * inv);
}

// ---------------------------------------------------------------------------
// 2) Weight transpose+convert: wt[mat][n][k] = bf16(W[mat][k][n])
//    mat = layer*4 + {0:q,1:k,2:v,3:o}.  Grid (12,12,8), 64x64 tiles.
// ---------------------------------------------------------------------------
__global__ __launch_bounds__(256) void wconv_kernel(
    const float* __restrict__ Wq, const float* __restrict__ Wk,
    const float* __restrict__ Wv, const float* __restrict__ Wo,
    __hip_bfloat16* __restrict__ wt)
{
    int mat = blockIdx.z;
    int layer = mat >> 2, which = mat & 3;
    const float* W = (which == 0 ? Wq : which == 1 ? Wk : which == 2 ? Wv : Wo)
                     + (size_t)layer * cH * cH;
    __shared__ float T[64][65];
    int k0 = blockIdx.y * 64, n0 = blockIdx.x * 64;
    int tid = threadIdx.x;
    int r = tid >> 2, cb = (tid & 3) * 16;
    #pragma unroll
    for (int u = 0; u < 4; ++u) {
        float4 w4 = *(const float4*)(W + (size_t)(k0 + r) * cH + n0 + cb + u * 4);
        T[r][cb + u * 4 + 0] = w4.x; T[r][cb + u * 4 + 1] = w4.y;
        T[r][cb + u * 4 + 2] = w4.z; T[r][cb + u * 4 + 3] = w4.w;
    }
    __syncthreads();
    int kk = tid & 63;
    int nb = (tid >> 6) * 16;
    __hip_bfloat16* dst = wt + ((size_t)mat * cH + n0) * cH + k0;
    #pragma unroll
    for (int u = 0; u < 16; ++u) {
        int nn = nb + u;
        dst[(size_t)nn * cH + kk] = __float2bfloat16(T[kk][nn]);
    }
}

// ---------------------------------------------------------------------------
// 3) MFMA bf16 GEMM: C_f32[512][768] = act(A_bf16[512][768] @ W + bias)
//    W given transposed: Wt_bf16[n][k].  Direct-from-global fragments (A/W
//    are L2-resident), no LDS, no barriers.  Grid (24, 8): block = 64 rows
//    (4 waves x 16) x 32 cols (2 n-tiles per wave).
//    Fragment maps (m89/m91-verified): a[j]=A[lane&15][q*8+j], b[j]=Wt[lane&15][q*8+j],
//    D: col=lane&15, row=q*4+r.
// ---------------------------------------------------------------------------
template<int ACT>
__global__ __launch_bounds__(256) void gemm_mfma(
    const __hip_bfloat16* __restrict__ A,
    const __hip_bfloat16* __restrict__ Wt,
    const float* __restrict__ bias,
    float* __restrict__ C)
{
    constexpr int K = cH, N = cH;
    int lane = threadIdx.x & 63;
    int wave = threadIdx.x >> 6;
    int l15 = lane & 15, q = lane >> 4;
    int m0 = blockIdx.y * 64 + wave * 16;
    int n0 = blockIdx.x * 32;

    const __hip_bfloat16* Arow = A  + (size_t)(m0 + l15) * K + q * 8;
    const __hip_bfloat16* Wr0  = Wt + (size_t)(n0 + l15) * K + q * 8;
    const __hip_bfloat16* Wr1  = Wr0 + (size_t)16 * K;

    f32x4 acc0 = {0.f, 0.f, 0.f, 0.f};
    f32x4 acc1 = {0.f, 0.f, 0.f, 0.f};
    #pragma unroll 4
    for (int k0 = 0; k0 < K; k0 += 32) {
        bf16x8 a  = *(const bf16x8*)(Arow + k0);
        bf16x8 b0 = *(const bf16x8*)(Wr0 + k0);
        bf16x8 b1 = *(const bf16x8*)(Wr1 + k0);
        acc0 = __builtin_amdgcn_mfma_f32_16x16x32_bf16(a, b0, acc0, 0, 0, 0);
        acc1 = __builtin_amdgcn_mfma_f32_16x16x32_bf16(a, b1, acc1, 0, 0, 0);
    }
    #pragma unroll
    for (int nt = 0; nt < 2; ++nt) {
        const f32x4 acc = nt == 0 ? acc0 : acc1;
        int col = n0 + nt * 16 + l15;
        float bv = bias[col];
        #pragma unroll
        for (int r = 0; r < 4; ++r) {
            int row = m0 + q * 4 + r;
            float v = acc[r] + bv;
            if (ACT == 1) v = 0.5f * v * (1.0f + erff(v * 0.70710678118654752f));
            C[(size_t)row * N + col] = v;
        }
    }
}

// ---------------------------------------------------------------------------
// 4) Fused per-head attention (fp32): scores -> softmax -> ctx (bf16 out).
//    One block per (b, head).  64x64 tiles in LDS, 4x4 register microtiles.
// ---------------------------------------------------------------------------
__global__ __launch_bounds__(256) void attn_kernel(
    const float* __restrict__ q, const float* __restrict__ k,
    const float* __restrict__ v, __hip_bfloat16* __restrict__ ctx)
{
    int bh = blockIdx.x;
    int b = bh / cNH, hh = bh % cNH;
    __shared__ float Qs[cNS][cDH + 4];
    __shared__ float Ks[cNS][cDH + 4];
    __shared__ float Vt[cDH][cNS + 4];
    __shared__ float Ps[cNS][cNS + 4];
    int tid = threadIdx.x;
    size_t base = ((size_t)b * cNS) * cH + hh * cDH;

    for (int i = tid; i < cNS * cDH / 4; i += 256) {
        int r = i >> 4;
        int c = (i & 15) << 2;
        float4 qv = *(const float4*)(q + base + (size_t)r * cH + c);
        float4 kv = *(const float4*)(k + base + (size_t)r * cH + c);
        float4 vv = *(const float4*)(v + base + (size_t)r * cH + c);
        *(float4*)&Qs[r][c] = qv;
        *(float4*)&Ks[r][c] = kv;
        Vt[c + 0][r] = vv.x; Vt[c + 1][r] = vv.y;
        Vt[c + 2][r] = vv.z; Vt[c + 3][r] = vv.w;
    }
    __syncthreads();

    int tx = tid & 15, ty = tid >> 4;  // 16 x 16 threads
    // scores: rows ty*4+i, cols tx + j*16
    float accs[4][4] = {};
    for (int d = 0; d < cDH; d += 4) {
        float4 qv[4], kv[4];
        #pragma unroll
        for (int i = 0; i < 4; ++i) qv[i] = *(const float4*)&Qs[ty * 4 + i][d];
        #pragma unroll
        for (int j = 0; j < 4; ++j) kv[j] = *(const float4*)&Ks[tx + j * 16][d];
        #pragma unroll
        for (int i = 0; i < 4; ++i)
            #pragma unroll
            for (int j = 0; j < 4; ++j)
                accs[i][j] += qv[i].x * kv[j].x + qv[i].y * kv[j].y +
                              qv[i].z * kv[j].z + qv[i].w * kv[j].w;
    }
    const float scale = 0.125f;  // 1/sqrt(64)
    #pragma unroll
    for (int i = 0; i < 4; ++i)
        #pragma unroll
        for (int j = 0; j < 4; ++j)
            Ps[ty * 4 + i][tx + j * 16] = accs[i][j] * scale;
    __syncthreads();

    // softmax: row = tid>>2, 16 cols per thread, quad shuffle reduction
    {
        int row = tid >> 2, jq = tid & 3;
        float e[16];
        float m = -1e30f;
        #pragma unroll
        for (int c = 0; c < 16; ++c) { e[c] = Ps[row][jq * 16 + c]; m = fmaxf(m, e[c]); }
        m = fmaxf(m, __shfl_xor(m, 1));
        m = fmaxf(m, __shfl_xor(m, 2));
        float s = 0.f;
        #pragma unroll
        for (int c = 0; c < 16; ++c) { e[c] = __expf(e[c] - m); s += e[c]; }
        s += __shfl_xor(s, 1);
        s += __shfl_xor(s, 2);
        float inv = 1.0f / s;
        #pragma unroll
        for (int c = 0; c < 16; ++c) Ps[row][jq * 16 + c] = e[c] * inv;
    }
    __syncthreads();

    // ctx: rows ty*4+i, dh cols tx + j*16, contract over 64 keys
    float acco[4][4] = {};
    for (int c = 0; c < cNS; c += 4) {
        float4 p4[4], vt4[4];
        #pragma unroll
        for (int i = 0; i < 4; ++i) p4[i] = *(const float4*)&Ps[ty * 4 + i][c];
        #pragma unroll
        for (int j = 0; j < 4; ++j) vt4[j] = *(const float4*)&Vt[tx + j * 16][c];
        #pragma unroll
        for (int i = 0; i < 4; ++i)
            #pragma unroll
            for (int j = 0; j < 4; ++j)
                acco[i][j] += p4[i].x * vt4[j].x + p4[i].y * vt4[j].y +
                              p4[i].z * vt4[j].z + p4[i].w * vt4[j].w;
    }
    #pragma unroll
    for (int i = 0; i < 4; ++i)
        #pragma unroll
        for (int j = 0; j < 4; ++j)
            ctx[base + (size_t)(ty * 4 + i) * cH + tx + j * 16] =
                __float2bfloat16(acco[i][j]);
}

// ---------------------------------------------------------------------------
// 5) LayerNorm over H=768: writes bf16 x (GEMM input) and optional f32 out.
// ---------------------------------------------------------------------------
__global__ __launch_bounds__(256) void ln_kernel(
    const float* __restrict__ h, const float* __restrict__ g,
    const float* __restrict__ bb, __hip_bfloat16* __restrict__ xb,
    float* __restrict__ outf)
{
    int row = blockIdx.x;
    const float* r = h + (size_t)row * cH;
    int tid = threadIdx.x;
    float v0 = r[tid], v1 = r[tid + 256], v2 = r[tid + 512];
    float s = v0 + v1 + v2;
    __shared__ float red[4];
    #pragma unroll
    for (int o = 32; o; o >>= 1) s += __shfl_xor(s, o);
    if ((tid & 63) == 0) red[tid >> 6] = s;
    __syncthreads();
    float mu = (red[0] + red[1] + red[2] + red[3]) * (1.0f / 768.0f);
    float d0 = v0 - mu, d1 = v1 - mu, d2 = v2 - mu;
    float ss = d0 * d0 + d1 * d1 + d2 * d2;
    __syncthreads();
    #pragma unroll
    for (int o = 32; o; o >>= 1) ss += __shfl_xor(ss, o);
    if ((tid & 63) == 0) red[tid >> 6] = ss;
    __syncthreads();
    float var = (red[0] + red[1] + red[2] + red[3]) * (1.0f / 768.0f);
    float inv = rsqrtf(var + 1e-12f);
    float o0 = d0 * inv * g[tid]       + bb[tid];
    float o1 = d1 * inv * g[tid + 256] + bb[tid + 256];
    float o2 = d2 * inv * g[tid + 512] + bb[tid + 512];
    __hip_bfloat16* xr = xb + (size_t)row * cH;
    xr[tid]       = __float2bfloat16(o0);
    xr[tid + 256] = __float2bfloat16(o1);
    xr[tid + 512] = __float2bfloat16(o2);
    if (outf) {
        float* orow = outf + (size_t)row * cH;
        orow[tid] = o0; orow[tid + 256] = o1; orow[tid + 512] = o2;
    }
}

// ---------------------------------------------------------------------------
extern "C" void kernel_launch(void* const* d_in, const int* in_sizes, int n_in,
                              void* d_out, int out_size, void* d_ws, size_t ws_size,
                              hipStream_t stream) {
    const int*   sent_ind = (const int*)d_in[0];
    const float* start    = (const float*)d_in[1];
    const float* Wq = (const float*)d_in[2];
    const float* bq = (const float*)d_in[3];
    const float* Wk = (const float*)d_in[4];
    const float* bk = (const float*)d_in[5];
    const float* Wv = (const float*)d_in[6];
    const float* bv = (const float*)d_in[7];
    const float* Wo = (const float*)d_in[8];
    const float* bo = (const float*)d_in[9];
    const float* ln_g = (const float*)d_in[10];
    const float* ln_b = (const float*)d_in[11];
    float* out = (float*)d_out;

    char* w = (char*)d_ws;
    __hip_bfloat16* wt     = (__hip_bfloat16*)w;                       // 8*768*768 bf16
    __hip_bfloat16* x_bf   = (__hip_bfloat16*)(w + 9437184);           // 512*768 bf16
    __hip_bfloat16* ctx_bf = (__hip_bfloat16*)(w + 9437184 + 786432);
    float* qb = (float*)(w + 9437184 + 2 * 786432);
    float* kb = qb + (size_t)cM * cH;
    float* vb = kb + (size_t)cM * cH;
    float* hb = vb + (size_t)cM * cH;

    wconv_kernel<<<dim3(12, 12, 8), 256, 0, stream>>>(Wq, Wk, Wv, Wo, wt);
    pool_kernel<<<cB * cNS, 256, 0, stream>>>(sent_ind, start, x_bf);

    for (int i = 0; i < cL; ++i) {
        const __hip_bfloat16* wtq = wt + (size_t)(i * 4 + 0) * cH * cH;
        const __hip_bfloat16* wtk = wt + (size_t)(i * 4 + 1) * cH * cH;
        const __hip_bfloat16* wtv = wt + (size_t)(i * 4 + 2) * cH * cH;
        const __hip_bfloat16* wto = wt + (size_t)(i * 4 + 3) * cH * cH;
        dim3 ggrid(24, 8);
        gemm_mfma<0><<<ggrid, 256, 0, stream>>>(x_bf, wtq, bq + (size_t)i * cH, qb);
        gemm_mfma<0><<<ggrid, 256, 0, stream>>>(x_bf, wtk, bk + (size_t)i * cH, kb);
        gemm_mfma<0><<<ggrid, 256, 0, stream>>>(x_bf, wtv, bv + (size_t)i * cH, vb);
        attn_kernel<<<cB * cNH, 256, 0, stream>>>(qb, kb, vb, ctx_bf);
        gemm_mfma<1><<<ggrid, 256, 0, stream>>>(ctx_bf, wto, bo + (size_t)i * cH, hb);
        ln_kernel<<<cM, 256, 0, stream>>>(hb, ln_g + (size_t)i * cH, ln_b + (size_t)i * cH,
                                          x_bf, (i == cL - 1) ? out : nullptr);
    }
}

// Round 3
// 292.459 us; speedup vs baseline: 1.0567x; 1.0567x over previous
//
#include <hip/hip_runtime.h>
#include <hip/hip_bf16.h>

// Problem constants (match reference)
constexpr int cB  = 8;
constexpr int cS  = 4096;
constexpr int cH  = 768;
constexpr int cNH = 12;
constexpr int cL  = 2;
constexpr int cNS = 64;
constexpr int cDH = 64;
constexpr int cM  = cB * cNS;  // 512 rows of activations

typedef __attribute__((ext_vector_type(8))) short bf16x8;
typedef __attribute__((ext_vector_type(4))) float f32x4;

// ---------------------------------------------------------------------------
// 1) Fused prep: blocks [0, 512) segment-mean pooling; blocks [512, 1664)
//    weight transpose+convert.  One launch overlaps both.
// ---------------------------------------------------------------------------
union PrepShared {                 // trivial union: no ctor (host-ctor breaks
    float T[64][65];               // __shared__ placement on device)
    struct { int cnt; int list[cS]; } p;
};

__global__ __launch_bounds__(256) void prep_kernel(
    const int* __restrict__ sent_ind, const float* __restrict__ sl,
    __hip_bfloat16* __restrict__ xb,
    const float* __restrict__ Wq, const float* __restrict__ Wk,
    const float* __restrict__ Wv, const float* __restrict__ Wo,
    __hip_bfloat16* __restrict__ wt)
{
    __shared__ PrepShared sh;
    int tid = threadIdx.x;

    if (blockIdx.x < (unsigned)cM) {
        // ---------------- pool ----------------
        int bn = blockIdx.x;
        int b = bn >> 6, n = bn & (cNS - 1);
        if (tid == 0) sh.p.cnt = 0;
        __syncthreads();
        const int* si = sent_ind + (size_t)b * cS;
        for (int s = tid; s < cS; s += 256)
            if (s != 0 && si[s] == n) { int p = atomicAdd(&sh.p.cnt, 1); sh.p.list[p] = s; }
        __syncthreads();
        int c = sh.p.cnt;
        if (tid < 192) {
            const float* bbase = sl + (size_t)b * cS * cH;
            int col = tid * 4;
            float4 a0 = {0.f, 0.f, 0.f, 0.f};
            float4 a1 = {0.f, 0.f, 0.f, 0.f};
            float4 a2 = {0.f, 0.f, 0.f, 0.f};
            float4 a3 = {0.f, 0.f, 0.f, 0.f};
            int i = 0;
            for (; i + 4 <= c; i += 4) {
                float4 r0 = *(const float4*)(bbase + (size_t)sh.p.list[i + 0] * cH + col);
                float4 r1 = *(const float4*)(bbase + (size_t)sh.p.list[i + 1] * cH + col);
                float4 r2 = *(const float4*)(bbase + (size_t)sh.p.list[i + 2] * cH + col);
                float4 r3 = *(const float4*)(bbase + (size_t)sh.p.list[i + 3] * cH + col);
                a0.x += r0.x; a0.y += r0.y; a0.z += r0.z; a0.w += r0.w;
                a1.x += r1.x; a1.y += r1.y; a1.z += r1.z; a1.w += r1.w;
                a2.x += r2.x; a2.y += r2.y; a2.z += r2.z; a2.w += r2.w;
                a3.x += r3.x; a3.y += r3.y; a3.z += r3.z; a3.w += r3.w;
            }
            for (; i < c; ++i) {
                float4 r0 = *(const float4*)(bbase + (size_t)sh.p.list[i] * cH + col);
                a0.x += r0.x; a0.y += r0.y; a0.z += r0.z; a0.w += r0.w;
            }
            float inv = 1.0f / (float)c;
            __hip_bfloat16* xr = xb + (size_t)bn * cH + col;
            xr[0] = __float2bfloat16((a0.x + a1.x + a2.x + a3.x) * inv);
            xr[1] = __float2bfloat16((a0.y + a1.y + a2.y + a3.y) * inv);
            xr[2] = __float2bfloat16((a0.z + a1.z + a2.z + a3.z) * inv);
            xr[3] = __float2bfloat16((a0.w + a1.w + a2.w + a3.w) * inv);
        }
    } else {
        // ---------------- wconv ----------------
        int bi = blockIdx.x - cM;           // 0..1151 = (12 x 12 x 8)
        int bx = bi % 12, by = (bi / 12) % 12, mat = bi / 144;
        int layer = mat >> 2, which = mat & 3;
        const float* W = (which == 0 ? Wq : which == 1 ? Wk : which == 2 ? Wv : Wo)
                         + (size_t)layer * cH * cH;
        int k0 = by * 64, n0 = bx * 64;
        int r = tid >> 2, cb = (tid & 3) * 16;
        #pragma unroll
        for (int u = 0; u < 4; ++u) {
            float4 w4 = *(const float4*)(W + (size_t)(k0 + r) * cH + n0 + cb + u * 4);
            sh.T[r][cb + u * 4 + 0] = w4.x; sh.T[r][cb + u * 4 + 1] = w4.y;
            sh.T[r][cb + u * 4 + 2] = w4.z; sh.T[r][cb + u * 4 + 3] = w4.w;
        }
        __syncthreads();
        int kk = tid & 63;
        int nb = (tid >> 6) * 16;
        __hip_bfloat16* dst = wt + ((size_t)mat * cH + n0) * cH + k0;
        #pragma unroll
        for (int u = 0; u < 16; ++u) {
            int nn = nb + u;
            dst[(size_t)nn * cH + kk] = __float2bfloat16(sh.T[kk][nn]);
        }
    }
}

// ---------------------------------------------------------------------------
// 2) MFMA bf16 GEMM.  Grid (24, 8, NMAT): 64 rows (4 waves x 16) x 32 cols.
//    NMAT=3 fuses q/k/v (Wt mats contiguous, per-mat bias pointer, per-mat
//    output stride M*H).  Fragment maps (m89/m91-verified):
//    a[j]=A[lane&15][q*8+j], b[j]=Wt[lane&15][q*8+j], D: col=lane&15, row=q*4+r.
// ---------------------------------------------------------------------------
template<int ACT>
__global__ __launch_bounds__(256) void gemm_mfma(
    const __hip_bfloat16* __restrict__ A,
    const __hip_bfloat16* __restrict__ Wt0,
    const float* __restrict__ biasA, const float* __restrict__ biasB,
    const float* __restrict__ biasC,
    float* __restrict__ C0)
{
    constexpr int K = cH, N = cH;
    int mat = blockIdx.z;
    const __hip_bfloat16* Wt = Wt0 + (size_t)mat * cH * cH;
    const float* bias = (mat == 0) ? biasA : (mat == 1) ? biasB : biasC;
    float* C = C0 + (size_t)mat * cM * cH;

    int lane = threadIdx.x & 63;
    int wave = threadIdx.x >> 6;
    int l15 = lane & 15, q = lane >> 4;
    int m0 = blockIdx.y * 64 + wave * 16;
    int n0 = blockIdx.x * 32;

    const __hip_bfloat16* Arow = A  + (size_t)(m0 + l15) * K + q * 8;
    const __hip_bfloat16* Wr0  = Wt + (size_t)(n0 + l15) * K + q * 8;
    const __hip_bfloat16* Wr1  = Wr0 + (size_t)16 * K;

    f32x4 acc0 = {0.f, 0.f, 0.f, 0.f};
    f32x4 acc1 = {0.f, 0.f, 0.f, 0.f};
    #pragma unroll 8
    for (int k0 = 0; k0 < K; k0 += 32) {
        bf16x8 a  = *(const bf16x8*)(Arow + k0);
        bf16x8 b0 = *(const bf16x8*)(Wr0 + k0);
        bf16x8 b1 = *(const bf16x8*)(Wr1 + k0);
        acc0 = __builtin_amdgcn_mfma_f32_16x16x32_bf16(a, b0, acc0, 0, 0, 0);
        acc1 = __builtin_amdgcn_mfma_f32_16x16x32_bf16(a, b1, acc1, 0, 0, 0);
    }
    #pragma unroll
    for (int nt = 0; nt < 2; ++nt) {
        const f32x4 acc = nt == 0 ? acc0 : acc1;
        int col = n0 + nt * 16 + l15;
        float bv = bias[col];
        #pragma unroll
        for (int r = 0; r < 4; ++r) {
            int row = m0 + q * 4 + r;
            float v = acc[r] + bv;
            if (ACT == 1) v = 0.5f * v * (1.0f + erff(v * 0.70710678118654752f));
            C[(size_t)row * N + col] = v;
        }
    }
}

// ---------------------------------------------------------------------------
// 3) Fused per-head attention (fp32).  One block per (b, head).
// ---------------------------------------------------------------------------
__global__ __launch_bounds__(256) void attn_kernel(
    const float* __restrict__ q, const float* __restrict__ k,
    const float* __restrict__ v, __hip_bfloat16* __restrict__ ctx)
{
    int bh = blockIdx.x;
    int b = bh / cNH, hh = bh % cNH;
    __shared__ float Qs[cNS][cDH + 4];
    __shared__ float Ks[cNS][cDH + 4];
    __shared__ float Vt[cDH][cNS + 4];
    __shared__ float Ps[cNS][cNS + 4];
    int tid = threadIdx.x;
    size_t base = ((size_t)b * cNS) * cH + hh * cDH;

    for (int i = tid; i < cNS * cDH / 4; i += 256) {
        int r = i >> 4;
        int c = (i & 15) << 2;
        float4 qv = *(const float4*)(q + base + (size_t)r * cH + c);
        float4 kv = *(const float4*)(k + base + (size_t)r * cH + c);
        float4 vv = *(const float4*)(v + base + (size_t)r * cH + c);
        *(float4*)&Qs[r][c] = qv;
        *(float4*)&Ks[r][c] = kv;
        Vt[c + 0][r] = vv.x; Vt[c + 1][r] = vv.y;
        Vt[c + 2][r] = vv.z; Vt[c + 3][r] = vv.w;
    }
    __syncthreads();

    int tx = tid & 15, ty = tid >> 4;  // 16 x 16 threads
    float accs[4][4] = {};
    for (int d = 0; d < cDH; d += 4) {
        float4 qv[4], kv[4];
        #pragma unroll
        for (int i = 0; i < 4; ++i) qv[i] = *(const float4*)&Qs[ty * 4 + i][d];
        #pragma unroll
        for (int j = 0; j < 4; ++j) kv[j] = *(const float4*)&Ks[tx + j * 16][d];
        #pragma unroll
        for (int i = 0; i < 4; ++i)
            #pragma unroll
            for (int j = 0; j < 4; ++j)
                accs[i][j] += qv[i].x * kv[j].x + qv[i].y * kv[j].y +
                              qv[i].z * kv[j].z + qv[i].w * kv[j].w;
    }
    const float scale = 0.125f;  // 1/sqrt(64)
    #pragma unroll
    for (int i = 0; i < 4; ++i)
        #pragma unroll
        for (int j = 0; j < 4; ++j)
            Ps[ty * 4 + i][tx + j * 16] = accs[i][j] * scale;
    __syncthreads();

    {
        int row = tid >> 2, jq = tid & 3;
        float e[16];
        float m = -1e30f;
        #pragma unroll
        for (int c = 0; c < 16; ++c) { e[c] = Ps[row][jq * 16 + c]; m = fmaxf(m, e[c]); }
        m = fmaxf(m, __shfl_xor(m, 1));
        m = fmaxf(m, __shfl_xor(m, 2));
        float s = 0.f;
        #pragma unroll
        for (int c = 0; c < 16; ++c) { e[c] = __expf(e[c] - m); s += e[c]; }
        s += __shfl_xor(s, 1);
        s += __shfl_xor(s, 2);
        float inv = 1.0f / s;
        #pragma unroll
        for (int c = 0; c < 16; ++c) Ps[row][jq * 16 + c] = e[c] * inv;
    }
    __syncthreads();

    float acco[4][4] = {};
    for (int c = 0; c < cNS; c += 4) {
        float4 p4[4], vt4[4];
        #pragma unroll
        for (int i = 0; i < 4; ++i) p4[i] = *(const float4*)&Ps[ty * 4 + i][c];
        #pragma unroll
        for (int j = 0; j < 4; ++j) vt4[j] = *(const float4*)&Vt[tx + j * 16][c];
        #pragma unroll
        for (int i = 0; i < 4; ++i)
            #pragma unroll
            for (int j = 0; j < 4; ++j)
                acco[i][j] += p4[i].x * vt4[j].x + p4[i].y * vt4[j].y +
                              p4[i].z * vt4[j].z + p4[i].w * vt4[j].w;
    }
    #pragma unroll
    for (int i = 0; i < 4; ++i)
        #pragma unroll
        for (int j = 0; j < 4; ++j)
            ctx[base + (size_t)(ty * 4 + i) * cH + tx + j * 16] =
                __float2bfloat16(acco[i][j]);
}

// ---------------------------------------------------------------------------
// 4) LayerNorm over H=768: writes bf16 x (GEMM input) and optional f32 out.
// ---------------------------------------------------------------------------
__global__ __launch_bounds__(256) void ln_kernel(
    const float* __restrict__ h, const float* __restrict__ g,
    const float* __restrict__ bb, __hip_bfloat16* __restrict__ xb,
    float* __restrict__ outf)
{
    int row = blockIdx.x;
    const float* r = h + (size_t)row * cH;
    int tid = threadIdx.x;
    float v0 = r[tid], v1 = r[tid + 256], v2 = r[tid + 512];
    float s = v0 + v1 + v2;
    __shared__ float red[4];
    #pragma unroll
    for (int o = 32; o; o >>= 1) s += __shfl_xor(s, o);
    if ((tid & 63) == 0) red[tid >> 6] = s;
    __syncthreads();
    float mu = (red[0] + red[1] + red[2] + red[3]) * (1.0f / 768.0f);
    float d0 = v0 - mu, d1 = v1 - mu, d2 = v2 - mu;
    float ss = d0 * d0 + d1 * d1 + d2 * d2;
    __syncthreads();
    #pragma unroll
    for (int o = 32; o; o >>= 1) ss += __shfl_xor(ss, o);
    if ((tid & 63) == 0) red[tid >> 6] = ss;
    __syncthreads();
    float var = (red[0] + red[1] + red[2] + red[3]) * (1.0f / 768.0f);
    float inv = rsqrtf(var + 1e-12f);
    float o0 = d0 * inv * g[tid]       + bb[tid];
    float o1 = d1 * inv * g[tid + 256] + bb[tid + 256];
    float o2 = d2 * inv * g[tid + 512] + bb[tid + 512];
    __hip_bfloat16* xr = xb + (size_t)row * cH;
    xr[tid]       = __float2bfloat16(o0);
    xr[tid + 256] = __float2bfloat16(o1);
    xr[tid + 512] = __float2bfloat16(o2);
    if (outf) {
        float* orow = outf + (size_t)row * cH;
        orow[tid] = o0; orow[tid + 256] = o1; orow[tid + 512] = o2;
    }
}

// ---------------------------------------------------------------------------
extern "C" void kernel_launch(void* const* d_in, const int* in_sizes, int n_in,
                              void* d_out, int out_size, void* d_ws, size_t ws_size,
                              hipStream_t stream) {
    const int*   sent_ind = (const int*)d_in[0];
    const float* start    = (const float*)d_in[1];
    const float* Wq = (const float*)d_in[2];
    const float* bq = (const float*)d_in[3];
    const float* Wk = (const float*)d_in[4];
    const float* bk = (const float*)d_in[5];
    const float* Wv = (const float*)d_in[6];
    const float* bv = (const float*)d_in[7];
    const float* Wo = (const float*)d_in[8];
    const float* bo = (const float*)d_in[9];
    const float* ln_g = (const float*)d_in[10];
    const float* ln_b = (const float*)d_in[11];
    float* out = (float*)d_out;

    char* w = (char*)d_ws;
    __hip_bfloat16* wt     = (__hip_bfloat16*)w;                       // 8*H*H bf16
    __hip_bfloat16* x_bf   = (__hip_bfloat16*)(w + 9437184);           // M*H bf16
    __hip_bfloat16* ctx_bf = (__hip_bfloat16*)(w + 9437184 + 786432);
    float* qb = (float*)(w + 9437184 + 2 * 786432);   // [3][M][H] f32 (q,k,v)
    float* hb = qb + (size_t)3 * cM * cH;

    prep_kernel<<<cM + 1152, 256, 0, stream>>>(sent_ind, start, x_bf,
                                               Wq, Wk, Wv, Wo, wt);

    for (int i = 0; i < cL; ++i) {
        const __hip_bfloat16* wtq = wt + (size_t)(i * 4 + 0) * cH * cH;  // q,k,v contiguous
        const __hip_bfloat16* wto = wt + (size_t)(i * 4 + 3) * cH * cH;
        gemm_mfma<0><<<dim3(24, 8, 3), 256, 0, stream>>>(
            x_bf, wtq, bq + (size_t)i * cH, bk + (size_t)i * cH, bv + (size_t)i * cH, qb);
        attn_kernel<<<cB * cNH, 256, 0, stream>>>(
            qb, qb + (size_t)cM * cH, qb + (size_t)2 * cM * cH, ctx_bf);
        gemm_mfma<1><<<dim3(24, 8, 1), 256, 0, stream>>>(
            ctx_bf, wto, bo + (size_t)i * cH, nullptr, nullptr, hb);
        ln_kernel<<<cM, 256, 0, stream>>>(hb, ln_g + (size_t)i * cH, ln_b + (size_t)i * cH,
                                          x_bf, (i == cL - 1) ? out : nullptr);
    }
}